// Round 6
// baseline (4564.287 us; speedup 1.0000x reference)
//
#include <hip/hip_runtime.h>
#include <math.h>

#define SS 2048
#define EE 1024
#define EPSD 1e-8
#define NTH 256          // 4 waves, 1 per SIMD
#define NW  4
#define NG  32           // cosine groups
#define GS  64           // group size

#define DPP_XOR1 0xB1    // quad_perm [1,0,3,2]
#define DPP_XOR2 0x4E    // quad_perm [2,3,0,1]
#define DPP_HMIR 0x141   // row_half_mirror
#define DPP_MIR  0x140   // row_mirror

template <typename T> struct VecT;
template <> struct VecT<double> { using t2 = double __attribute__((ext_vector_type(2))); };
template <> struct VecT<float>  { using t2 = float  __attribute__((ext_vector_type(2))); };

template <int CTRL>
__device__ __forceinline__ double mov_dpp_f64(double v) {
  union { double d; unsigned long long u; } a;
  a.d = v;
  const int lo = (int)(unsigned)(a.u & 0xFFFFFFFFull);
  const int hi = (int)(unsigned)(a.u >> 32);
  const int nlo = __builtin_amdgcn_mov_dpp(lo, CTRL, 0xF, 0xF, true);
  const int nhi = __builtin_amdgcn_mov_dpp(hi, CTRL, 0xF, 0xF, true);
  union { unsigned long long u; double d; } r;
  r.u = ((unsigned long long)(unsigned)nhi << 32) | (unsigned long long)(unsigned)nlo;
  return r.d;
}

template <int CTRL>
__device__ __forceinline__ double dpp_add(double v) { return v + mov_dpp_f64<CTRL>(v); }

template <int CTRL>
__device__ __forceinline__ void amax_dpp(double& v, int& ix) {
  const double ov = mov_dpp_f64<CTRL>(v);
  const int oi = __builtin_amdgcn_mov_dpp(ix, CTRL, 0xF, 0xF, true);
  if (ov > v || (ov == v && oi < ix)) { v = ov; ix = oi; }
}

__device__ __forceinline__ void amax_xor(double& v, int& ix, int m) {
  const double ov = __shfl_xor(v, m, 64);
  const int oi = __shfl_xor(ix, m, 64);
  if (ov > v || (ov == v && oi < ix)) { v = ov; ix = oi; }
}

__device__ __forceinline__ void foldmax(double& v, int& ix, double ov, int oi) {
  if (ov > v || (ov == v && oi < ix)) { v = ov; ix = oi; }
}

// 1/sqrt(x), ~1-2 ulp: v_rsq_f64 + 2 Newton iterations.
__device__ __forceinline__ double rsqrt2(double x) {
  double y = __builtin_amdgcn_rsq(x);
  const double h = 0.5 * x;
  y = y * fma(-h * y, y, 1.5);
  y = y * fma(-h * y, y, 1.5);
  return y;
}

__device__ __forceinline__ double wave_sum64(double v) {
#pragma unroll
  for (int off = 32; off > 0; off >>= 1) v += __shfl_down(v, off, 64);
  return v;
}

// ~1e-13-accurate branchless f64 tanh for |z| <~ 1.2.
__device__ __forceinline__ double tanh_fast(double z) {
  const double u = 0.5 * z;
  const double s = u * u;
  double p = -113927491862.0 / 2900518163668125.0;
  p = fma(p, s, 18888466084.0 / 194896477400625.0);
  p = fma(p, s, -443861162.0 / 1856156927625.0);
  p = fma(p, s, 6404582.0 / 10854718875.0);
  p = fma(p, s, -929569.0 / 638512875.0);
  p = fma(p, s, 21844.0 / 6081075.0);
  p = fma(p, s, -1382.0 / 155925.0);
  p = fma(p, s, 62.0 / 2835.0);
  p = fma(p, s, -17.0 / 315.0);
  p = fma(p, s, 2.0 / 15.0);
  p = fma(p, s, -1.0 / 3.0);
  const double t = fma(u * s, p, u);          // tanh(z/2)
  return (2.0 * t) / fma(t, t, 1.0);
}

template <typename T>
__global__ void banyan_init(const int* __restrict__ seqs, const float* __restrict__ emb,
                            T* __restrict__ x, double* __restrict__ norms) {
  __shared__ double sh[4];
  const int s = blockIdx.x;
  const int row = seqs[s];
  double acc = 0.0;
  for (int e = threadIdx.x; e < EE; e += 256) {
    const float v = emb[(size_t)row * EE + e];
    x[(size_t)s * EE + e] = (T)v;
    acc += (double)v * (double)v;
  }
  acc = wave_sum64(acc);
  const int lane = threadIdx.x & 63;
  const int w = threadIdx.x >> 6;
  if (lane == 0) sh[w] = acc;
  __syncthreads();
  if (threadIdx.x == 0) norms[s] = sqrt(sh[0] + sh[1] + sh[2] + sh[3]);
}

template <typename T>
__global__ void banyan_dots(const T* __restrict__ x, double* __restrict__ num) {
  __shared__ double sh[4];
  const int s = blockIdx.x;
  double acc = 0.0;
  for (int e = threadIdx.x; e < EE; e += 256) {
    acc += (double)x[(size_t)s * EE + e] * (double)x[(size_t)(s + 1) * EE + e];
  }
  acc = wave_sum64(acc);
  const int lane = threadIdx.x & 63;
  const int w = threadIdx.x >> 6;
  if (lane == 0) sh[w] = acc;
  __syncthreads();
  if (threadIdx.x == 0) num[s] = sh[0] + sh[1] + sh[2] + sh[3];
}

// Persistent single-block merge loop, software-pipelined:
// loads for step k issued right after barrier C of step k-1, consumed after
// zone-A scans (S-scan + stable-group scans) that run under the load latency.
template <typename T>
__global__ __launch_bounds__(NTH, 1) void banyan_main(
    T* __restrict__ x, const double* __restrict__ norms_in, const double* __restrict__ num_in,
    const float* __restrict__ Wl, const float* __restrict__ Wr, const float* __restrict__ Bb,
    float* __restrict__ out) {
  __shared__ double cosL[SS];
  __shared__ double rcpN[SS];      // 1 / max(norm, eps)
  __shared__ unsigned listL[SS];   // next lo16, prev hi16 (0xFFFF = -1)
  __shared__ int next2L[SS];       // next[next[s]] (-1 = none)
  __shared__ double gVal[NG];
  __shared__ int gIdx[NG];
  __shared__ double r3v[NW * 2 * 3];  // [half-slot][3]
  __shared__ double r4v[3];           // stable-scan maxima of touched groups
  __shared__ int r4i[3];

  using T2 = typename VecT<T>::t2;
  const int t = threadIdx.x;
  const int lane = t & 63;
  const int w = t >> 6;
  const double NEGINF = -__builtin_inf();

  for (int s = t; s < SS; s += NTH) {
    rcpN[s] = 1.0 / fmax(norms_in[s], EPSD);
    const int nx = (s + 1 < SS) ? (s + 1) : -1;
    const int pv = s - 1;
    listL[s] = ((unsigned)nx & 0xFFFFu) | (((unsigned)pv & 0xFFFFu) << 16);
    next2L[s] = (s + 2 < SS) ? (s + 2) : -1;
  }
  __syncthreads();
  for (int s = t; s < SS; s += NTH) {
    cosL[s] = (s < SS - 1) ? (num_in[s] * rcpN[s]) * rcpN[s + 1] : NEGINF;
  }
  __syncthreads();
  for (int m = 0; m < NG / NW; ++m) {
    const int g = w * (NG / NW) + m;
    double v = cosL[g * GS + lane];
    int ix = g * GS + lane;
#pragma unroll
    for (int off = 32; off > 0; off >>= 1) {
      const double ov = __shfl_down(v, off, 64);
      const int oi = __shfl_down(ix, off, 64);
      if (ov > v || (ov == v && oi < ix)) { v = ov; ix = oi; }
    }
    if (lane == 0) { gVal[g] = v; gIdx[g] = ix; }
  }
  __syncthreads();

  // Thread t owns elements {2t, 2t+1, 512+2t, 512+2t+1}.
  const int e0 = 2 * t;
  const double wl0 = (double)Wl[e0],       wl1 = (double)Wl[e0 + 1];
  const double wl2 = (double)Wl[e0 + 512], wl3 = (double)Wl[e0 + 513];
  const double wr0 = (double)Wr[e0],       wr1 = (double)Wr[e0 + 1];
  const double wr2 = (double)Wr[e0 + 512], wr3 = (double)Wr[e0 + 513];
  const double bv0 = (double)Bb[e0],       bv1 = (double)Bb[e0 + 1];
  const double bv2 = (double)Bb[e0 + 512], bv3 = (double)Bb[e0 + 513];
  int head = 0;

  // ---- prologue: full argmax -> first quad -> issue first loads ----
  int i, j, p, nj, p2, n2, j2;
  {
    double v = gVal[lane & 31];
    int ix = gIdx[lane & 31];
    amax_dpp<DPP_XOR1>(v, ix); amax_dpp<DPP_XOR2>(v, ix);
    amax_dpp<DPP_HMIR>(v, ix); amax_dpp<DPP_MIR>(v, ix);
    amax_xor(v, ix, 16);
    i = __builtin_amdgcn_readfirstlane(ix);
    const unsigned pki = listL[i];
    j = (int)(short)(pki & 0xFFFFu);
    p = (int)(short)(pki >> 16);
    nj = next2L[i];
    p2 = (p >= 0) ? p : i;
    n2 = (nj >= 0) ? nj : i;
    j2 = (j >= 0) ? j : i;
  }
  T2 Lxi0, Lxi1, Lxj0, Lxj1, Lxp0, Lxp1, Lxn0, Lxn1;
#define ISSUE_LOADS() do {                                  \
    Lxi0 = *(const T2*)&x[(size_t)i * EE + e0];             \
    Lxi1 = *(const T2*)&x[(size_t)i * EE + e0 + 512];       \
    Lxj0 = *(const T2*)&x[(size_t)j2 * EE + e0];            \
    Lxj1 = *(const T2*)&x[(size_t)j2 * EE + e0 + 512];      \
    Lxp0 = *(const T2*)&x[(size_t)p2 * EE + e0];            \
    Lxp1 = *(const T2*)&x[(size_t)p2 * EE + e0 + 512];      \
    Lxn0 = *(const T2*)&x[(size_t)n2 * EE + e0];            \
    Lxn1 = *(const T2*)&x[(size_t)n2 * EE + e0 + 512];      \
  } while (0)
  ISSUE_LOADS();

  for (int step = 0; step < SS - 1; ++step) {
    if (p < 0) head = j;
    const int gi_ = i >> 6;
    const int gp_ = (p >= 0) ? (p >> 6) : gi_;
    const int gj_ = j >> 6;

    // ---- zone A (loads in flight): S-scan, stable scans, pre-reads ----
    double Sv; int Si;
    {
      const int g = lane & 31;
      const bool excl = (g == gi_) | (g == gp_) | (g == gj_);
      Sv = excl ? NEGINF : gVal[g];
      Si = gIdx[g];
      amax_dpp<DPP_XOR1>(Sv, Si); amax_dpp<DPP_XOR2>(Sv, Si);
      amax_dpp<DPP_HMIR>(Sv, Si); amax_dpp<DPP_MIR>(Sv, Si);
      amax_xor(Sv, Si, 16);
    }
    const int SiU = __builtin_amdgcn_readfirstlane(Si);
    const unsigned listS = listL[SiU];
    const int Snext = (int)(short)(listS & 0xFFFFu);
    const int Sprev = (int)(short)(listS >> 16);
    const int next2S = next2L[SiU];
    const unsigned listP = listL[p2];
    const int pp = (p >= 0) ? (int)(short)(listP >> 16) : -1;
    const int nj2J = next2L[j2];
    const double rcpP = rcpN[p2];
    const double rcpNN = rcpN[n2];
    const int grp = (w == 0) ? gi_ : (w == 1) ? gp_ : gj_;
    double stv = NEGINF; int sti = 0;
    if (w < 3) {
      const int pos = grp * GS + lane;
      double c = cosL[pos];
      if (pos == i || pos == p || pos == j) c = NEGINF;  // replaced post-B
      int cx = pos;
      amax_dpp<DPP_XOR1>(c, cx); amax_dpp<DPP_XOR2>(c, cx);
      amax_dpp<DPP_HMIR>(c, cx); amax_dpp<DPP_MIR>(c, cx);
      amax_xor(c, cx, 16); amax_xor(c, cx, 32);
      stv = c; sti = cx;
      if (lane == 0) { r4v[w] = c; r4i[w] = cx; }
    }

    // ---- consume loads: tanh, store parent, fused 3-sum, DPP reduce ----
    const double q0 = tanh_fast(fma((double)Lxi0.x, wl0, fma((double)Lxj0.x, wr0, bv0)));
    const double q1 = tanh_fast(fma((double)Lxi0.y, wl1, fma((double)Lxj0.y, wr1, bv1)));
    const double q2 = tanh_fast(fma((double)Lxi1.x, wl2, fma((double)Lxj1.x, wr2, bv2)));
    const double q3 = tanh_fast(fma((double)Lxi1.y, wl3, fma((double)Lxj1.y, wr3, bv3)));
    T2 st0; st0.x = (T)q0; st0.y = (T)q1;
    T2 st1; st1.x = (T)q2; st1.y = (T)q3;
    *(T2*)&x[(size_t)j * EE + e0] = st0;
    *(T2*)&x[(size_t)j * EE + e0 + 512] = st1;
    double s0 = fma(q0, q0, fma(q1, q1, fma(q2, q2, q3 * q3)));
    double s1 = fma((double)Lxp0.x, q0, fma((double)Lxp0.y, q1,
                fma((double)Lxp1.x, q2, (double)Lxp1.y * q3)));
    double s2 = fma(q0, (double)Lxn0.x, fma(q1, (double)Lxn0.y,
                fma(q2, (double)Lxn1.x, q3 * (double)Lxn1.y)));
    s1 = (p >= 0) ? s1 : 0.0;
    s2 = (nj >= 0) ? s2 : 0.0;
    s0 = dpp_add<DPP_XOR1>(s0); s1 = dpp_add<DPP_XOR1>(s1); s2 = dpp_add<DPP_XOR1>(s2);
    s0 = dpp_add<DPP_XOR2>(s0); s1 = dpp_add<DPP_XOR2>(s1); s2 = dpp_add<DPP_XOR2>(s2);
    s0 = dpp_add<DPP_HMIR>(s0); s1 = dpp_add<DPP_HMIR>(s1); s2 = dpp_add<DPP_HMIR>(s2);
    s0 = dpp_add<DPP_MIR>(s0);  s1 = dpp_add<DPP_MIR>(s1);  s2 = dpp_add<DPP_MIR>(s2);
    s0 += __shfl_xor(s0, 16, 64);
    s1 += __shfl_xor(s1, 16, 64);
    s2 += __shfl_xor(s2, 16, 64);
    if ((lane & 31) == 0) {
      const int slot = w * 2 + (lane >> 5);
      r3v[slot * 3 + 0] = s0; r3v[slot * 3 + 1] = s1; r3v[slot * 3 + 2] = s2;
    }
    __syncthreads();  // B

    // ---- post-B: finish sums, cosines, 6-way argmax, select next quad ----
    const double U0v = r4v[0], U1v = r4v[1], U2v = r4v[2];
    const int U0i = r4i[0], U1i = r4i[1], U2i = r4i[2];
    double t0 = 0.0, t1 = 0.0, t2 = 0.0;
#pragma unroll
    for (int m = 0; m < NW * 2; ++m) {
      t0 += r3v[m * 3 + 0]; t1 += r3v[m * 3 + 1]; t2 += r3v[m * 3 + 2];
    }
    const double invnn = (t0 > EPSD * EPSD) ? rsqrt2(t0) : (1.0 / EPSD);
    const double cosP = (p >= 0) ? (t1 * rcpP) * invnn : NEGINF;
    const double cosJ = (nj >= 0) ? (t2 * rcpNN) * invnn : NEGINF;
    double bvv = Sv; int bii = Si;
    foldmax(bvv, bii, U0v, U0i);
    foldmax(bvv, bii, U1v, U1i);
    foldmax(bvv, bii, U2v, U2i);
    foldmax(bvv, bii, cosP, p);
    foldmax(bvv, bii, cosJ, j);
    const int iN = __builtin_amdgcn_readfirstlane(bii);
    int jN, pN, njN;
    if (iN == p)        { jN = j;     pN = pp;    njN = nj;    }
    else if (iN == j)   { jN = nj;    pN = p;     njN = nj2J;  }
    else if (iN == SiU) { jN = Snext; pN = Sprev; njN = next2S; }
    else {
      const unsigned pkiU = listL[iN];   // iN not in {p,j}: stable words
      jN = (int)(short)(pkiU & 0xFFFFu);
      pN = (int)(short)(pkiU >> 16);
      njN = next2L[iN];
    }
    if (iN != p && iN != j && iN == pp) njN = j;  // next2 staleness fix

    // ---- repairs with OLD (i,j,p): O(1) gVal update + scalar writes ----
    if (w < 3) {
      double nv = stv; int ni = sti;
      if (p >= 0 && (p >> 6) == grp) foldmax(nv, ni, cosP, p);
      if ((j >> 6) == grp) foldmax(nv, ni, cosJ, j);
      if (lane == 0) { gVal[grp] = nv; gIdx[grp] = ni; }
    } else if (lane == 0) {
      cosL[i] = NEGINF;
      cosL[j] = cosJ;           // -inf when nj < 0
      rcpN[j] = invnn;
      listL[j] = ((unsigned)nj & 0xFFFFu) | (((unsigned)p & 0xFFFFu) << 16);
      if (p >= 0) {
        cosL[p] = cosP;
        listL[p] = (listP & 0xFFFF0000u) | ((unsigned)j & 0xFFFFu);
        next2L[p] = nj;
        if (pp >= 0) next2L[pp] = j;
      }
    }
    // commit new quad
    i = iN; j = jN; p = pN; nj = njN;
    p2 = (p >= 0) ? p : i;
    n2 = (nj >= 0) ? nj : i;
    j2 = (j >= 0) ? j : i;
    __syncthreads();  // C
    // ---- issue next step's loads (fly across zone A, no barrier between) ----
    ISSUE_LOADS();
  }
#undef ISSUE_LOADS

  {
    const T2 ha = *(const T2*)&x[(size_t)head * EE + e0];
    const T2 hb = *(const T2*)&x[(size_t)head * EE + e0 + 512];
    out[e0] = (float)ha.x;
    out[e0 + 1] = (float)ha.y;
    out[e0 + 512] = (float)hb.x;
    out[e0 + 513] = (float)hb.y;
  }
}

extern "C" void kernel_launch(void* const* d_in, const int* in_sizes, int n_in,
                              void* d_out, int out_size, void* d_ws, size_t ws_size,
                              hipStream_t stream) {
  const int* seqs = (const int*)d_in[0];
  const float* emb = (const float*)d_in[1];
  const float* Wl = (const float*)d_in[2];
  const float* Wr = (const float*)d_in[3];
  const float* Bb = (const float*)d_in[4];
  float* out = (float*)d_out;

  const size_t auxBytes = 2 * (size_t)SS * sizeof(double);
  const size_t xbytesD = (size_t)SS * EE * sizeof(double);

  if (ws_size >= xbytesD + auxBytes) {
    double* x = (double*)d_ws;
    double* norms = (double*)((char*)d_ws + xbytesD);
    double* num = norms + SS;
    hipLaunchKernelGGL((banyan_init<double>), dim3(SS), dim3(256), 0, stream, seqs, emb, x, norms);
    hipLaunchKernelGGL((banyan_dots<double>), dim3(SS - 1), dim3(256), 0, stream, x, num);
    hipLaunchKernelGGL((banyan_main<double>), dim3(1), dim3(NTH), 0, stream,
                       x, norms, num, Wl, Wr, Bb, out);
  } else {
    const size_t xbytesF = (size_t)SS * EE * sizeof(float);
    float* x = (float*)d_ws;
    double* norms = (double*)((char*)d_ws + xbytesF);
    double* num = norms + SS;
    hipLaunchKernelGGL((banyan_init<float>), dim3(SS), dim3(256), 0, stream, seqs, emb, x, norms);
    hipLaunchKernelGGL((banyan_dots<float>), dim3(SS - 1), dim3(256), 0, stream, x, num);
    hipLaunchKernelGGL((banyan_main<float>), dim3(1), dim3(NTH), 0, stream,
                       x, norms, num, Wl, Wr, Bb, out);
  }
}

// Round 8
// 4462.574 us; speedup vs baseline: 1.0228x; 1.0228x over previous
//
#include <hip/hip_runtime.h>
#include <math.h>

#define SS 2048
#define EE 1024
#define EPSD 1e-8
#define NTH 256          // 4 waves, 1 per SIMD
#define NW  4
#define NG  32           // cosine groups
#define GS  64           // group size

#define DPP_XOR1 0xB1    // quad_perm [1,0,3,2]
#define DPP_XOR2 0x4E    // quad_perm [2,3,0,1]
#define DPP_HMIR 0x141   // row_half_mirror
#define DPP_MIR  0x140   // row_mirror

template <typename T> struct VecT;
template <> struct VecT<double> { using t2 = double __attribute__((ext_vector_type(2))); };
template <> struct VecT<float>  { using t2 = float  __attribute__((ext_vector_type(2))); };

template <int CTRL>
__device__ __forceinline__ double mov_dpp_f64(double v) {
  union { double d; unsigned long long u; } a;
  a.d = v;
  const int lo = (int)(unsigned)(a.u & 0xFFFFFFFFull);
  const int hi = (int)(unsigned)(a.u >> 32);
  const int nlo = __builtin_amdgcn_mov_dpp(lo, CTRL, 0xF, 0xF, true);
  const int nhi = __builtin_amdgcn_mov_dpp(hi, CTRL, 0xF, 0xF, true);
  union { unsigned long long u; double d; } r;
  r.u = ((unsigned long long)(unsigned)nhi << 32) | (unsigned long long)(unsigned)nlo;
  return r.d;
}

template <int CTRL>
__device__ __forceinline__ double dpp_add(double v) { return v + mov_dpp_f64<CTRL>(v); }

template <int CTRL>
__device__ __forceinline__ void amax_dpp(double& v, int& ix) {
  const double ov = mov_dpp_f64<CTRL>(v);
  const int oi = __builtin_amdgcn_mov_dpp(ix, CTRL, 0xF, 0xF, true);
  if (ov > v || (ov == v && oi < ix)) { v = ov; ix = oi; }
}

__device__ __forceinline__ void amax_xor(double& v, int& ix, int m) {
  const double ov = __shfl_xor(v, m, 64);
  const int oi = __shfl_xor(ix, m, 64);
  if (ov > v || (ov == v && oi < ix)) { v = ov; ix = oi; }
}

__device__ __forceinline__ void foldmax(double& v, int& ix, double ov, int oi) {
  if (ov > v || (ov == v && oi < ix)) { v = ov; ix = oi; }
}

// 1/sqrt(x), ~1-2 ulp: v_rsq_f64 + 2 Newton iterations.
__device__ __forceinline__ double rsqrt2(double x) {
  double y = __builtin_amdgcn_rsq(x);
  const double h = 0.5 * x;
  y = y * fma(-h * y, y, 1.5);
  y = y * fma(-h * y, y, 1.5);
  return y;
}

// 1/x, ~1 ulp: v_rcp_f64 + 2 Newton iterations (avoids IEEE div chain).
__device__ __forceinline__ double rcp2(double x) {
  double y = __builtin_amdgcn_rcp(x);
  y = y * fma(-x, y, 2.0);
  y = y * fma(-x, y, 2.0);
  return y;
}

__device__ __forceinline__ double wave_sum64(double v) {
#pragma unroll
  for (int off = 32; off > 0; off >>= 1) v += __shfl_down(v, off, 64);
  return v;
}

// ~1e-13-accurate branchless f64 tanh for |z| <~ 1.2.
__device__ __forceinline__ double tanh_fast(double z) {
  const double u = 0.5 * z;
  const double s = u * u;
  double p = -113927491862.0 / 2900518163668125.0;
  p = fma(p, s, 18888466084.0 / 194896477400625.0);
  p = fma(p, s, -443861162.0 / 1856156927625.0);
  p = fma(p, s, 6404582.0 / 10854718875.0);
  p = fma(p, s, -929569.0 / 638512875.0);
  p = fma(p, s, 21844.0 / 6081075.0);
  p = fma(p, s, -1382.0 / 155925.0);
  p = fma(p, s, 62.0 / 2835.0);
  p = fma(p, s, -17.0 / 315.0);
  p = fma(p, s, 2.0 / 15.0);
  p = fma(p, s, -1.0 / 3.0);
  const double t = fma(u * s, p, u);          // tanh(z/2)
  return (2.0 * t) * rcp2(fma(t, t, 1.0));
}

template <typename T>
__global__ void banyan_init(const int* __restrict__ seqs, const float* __restrict__ emb,
                            T* __restrict__ x, double* __restrict__ norms) {
  __shared__ double sh[4];
  const int s = blockIdx.x;
  const int row = seqs[s];
  double acc = 0.0;
  for (int e = threadIdx.x; e < EE; e += 256) {
    const float v = emb[(size_t)row * EE + e];
    x[(size_t)s * EE + e] = (T)v;
    acc += (double)v * (double)v;
  }
  acc = wave_sum64(acc);
  const int lane = threadIdx.x & 63;
  const int w = threadIdx.x >> 6;
  if (lane == 0) sh[w] = acc;
  __syncthreads();
  if (threadIdx.x == 0) norms[s] = sqrt(sh[0] + sh[1] + sh[2] + sh[3]);
}

template <typename T>
__global__ void banyan_dots(const T* __restrict__ x, double* __restrict__ num) {
  __shared__ double sh[4];
  const int s = blockIdx.x;
  double acc = 0.0;
  for (int e = threadIdx.x; e < EE; e += 256) {
    acc += (double)x[(size_t)s * EE + e] * (double)x[(size_t)(s + 1) * EE + e];
  }
  acc = wave_sum64(acc);
  const int lane = threadIdx.x & 63;
  const int w = threadIdx.x >> 6;
  if (lane == 0) sh[w] = acc;
  __syncthreads();
  if (threadIdx.x == 0) num[s] = sh[0] + sh[1] + sh[2] + sh[3];
}

// Persistent single-block merge loop, software-pipelined. Loads for step k
// issue right after barrier C of step k-1, PINNED by sched_barrier(0).
// All prefetch indices are masked & (SS-1): identity for real steps, clamps
// the degenerate post-final-merge phantom quad (R7 faulted on exactly that).
template <typename T>
__global__ __launch_bounds__(NTH, 1) void banyan_main(
    T* __restrict__ x, const double* __restrict__ norms_in, const double* __restrict__ num_in,
    const float* __restrict__ Wl, const float* __restrict__ Wr, const float* __restrict__ Bb,
    float* __restrict__ out) {
  __shared__ double cosL[SS];
  __shared__ double rcpN[SS];      // 1 / max(norm, eps)
  __shared__ unsigned listL[SS];   // next lo16, prev hi16 (0xFFFF = -1)
  __shared__ int next2L[SS];       // next[next[s]] (-1 = none)
  __shared__ double gVal[NG];
  __shared__ int gIdx[NG];
  __shared__ double r3v[NW * 2 * 3];  // [half-slot][3]
  __shared__ double r4v[3];           // stable-scan maxima of touched groups
  __shared__ int r4i[3];

  using T2 = typename VecT<T>::t2;
  const int t = threadIdx.x;
  const int lane = t & 63;
  const int w = t >> 6;
  const double NEGINF = -__builtin_inf();

  for (int s = t; s < SS; s += NTH) {
    rcpN[s] = 1.0 / fmax(norms_in[s], EPSD);
    const int nx = (s + 1 < SS) ? (s + 1) : -1;
    const int pv = s - 1;
    listL[s] = ((unsigned)nx & 0xFFFFu) | (((unsigned)pv & 0xFFFFu) << 16);
    next2L[s] = (s + 2 < SS) ? (s + 2) : -1;
  }
  __syncthreads();
  for (int s = t; s < SS; s += NTH) {
    cosL[s] = (s < SS - 1) ? (num_in[s] * rcpN[s]) * rcpN[s + 1] : NEGINF;
  }
  __syncthreads();
  for (int m = 0; m < NG / NW; ++m) {
    const int g = w * (NG / NW) + m;
    double v = cosL[g * GS + lane];
    int ix = g * GS + lane;
#pragma unroll
    for (int off = 32; off > 0; off >>= 1) {
      const double ov = __shfl_down(v, off, 64);
      const int oi = __shfl_down(ix, off, 64);
      if (ov > v || (ov == v && oi < ix)) { v = ov; ix = oi; }
    }
    if (lane == 0) { gVal[g] = v; gIdx[g] = ix; }
  }
  __syncthreads();

  // Thread t owns elements {2t, 2t+1, 512+2t, 512+2t+1}.
  const int e0 = 2 * t;
  const double wl0 = (double)Wl[e0],       wl1 = (double)Wl[e0 + 1];
  const double wl2 = (double)Wl[e0 + 512], wl3 = (double)Wl[e0 + 513];
  const double wr0 = (double)Wr[e0],       wr1 = (double)Wr[e0 + 1];
  const double wr2 = (double)Wr[e0 + 512], wr3 = (double)Wr[e0 + 513];
  const double bv0 = (double)Bb[e0],       bv1 = (double)Bb[e0 + 1];
  const double bv2 = (double)Bb[e0 + 512], bv3 = (double)Bb[e0 + 513];
  int head = 0;

  // ---- prologue: full argmax -> first quad -> issue first loads ----
  int i, j, p, nj, p2, n2, j2;
  {
    double v = gVal[lane & 31];
    int ix = gIdx[lane & 31];
    amax_dpp<DPP_XOR1>(v, ix); amax_dpp<DPP_XOR2>(v, ix);
    amax_dpp<DPP_HMIR>(v, ix); amax_dpp<DPP_MIR>(v, ix);
    amax_xor(v, ix, 16);
    i = __builtin_amdgcn_readfirstlane(ix);
    const unsigned pki = listL[i];
    j = (int)(short)(pki & 0xFFFFu);
    p = (int)(short)(pki >> 16);
    nj = next2L[i];
    p2 = (p >= 0) ? p : i;
    n2 = (nj >= 0) ? nj : i;
    j2 = (j >= 0) ? j : i;
  }
  T2 Lxi0, Lxi1, Lxj0, Lxj1, Lxp0, Lxp1, Lxn0, Lxn1;
#define ISSUE_LOADS() do {                                  \
    const int iM = i & (SS - 1);                            \
    const int jM = j2 & (SS - 1);                           \
    const int pM = p2 & (SS - 1);                           \
    const int nM = n2 & (SS - 1);                           \
    Lxi0 = *(const T2*)&x[(size_t)iM * EE + e0];            \
    Lxi1 = *(const T2*)&x[(size_t)iM * EE + e0 + 512];      \
    Lxj0 = *(const T2*)&x[(size_t)jM * EE + e0];            \
    Lxj1 = *(const T2*)&x[(size_t)jM * EE + e0 + 512];      \
    Lxp0 = *(const T2*)&x[(size_t)pM * EE + e0];            \
    Lxp1 = *(const T2*)&x[(size_t)pM * EE + e0 + 512];      \
    Lxn0 = *(const T2*)&x[(size_t)nM * EE + e0];            \
    Lxn1 = *(const T2*)&x[(size_t)nM * EE + e0 + 512];      \
    __builtin_amdgcn_sched_barrier(0);                      \
  } while (0)
  ISSUE_LOADS();

  for (int step = 0; step < SS - 1; ++step) {
    if (p < 0) head = j;
    const int gi_ = i >> 6;
    const int gp_ = (p >= 0) ? (p >> 6) : gi_;
    const int gj_ = j >> 6;

    // ---- zone A (loads in flight): S-scan, stable scans, pre-reads ----
    double Sv; int Si;
    {
      const int g = lane & 31;
      const bool excl = (g == gi_) | (g == gp_) | (g == gj_);
      Sv = excl ? NEGINF : gVal[g];
      Si = gIdx[g];
      amax_dpp<DPP_XOR1>(Sv, Si); amax_dpp<DPP_XOR2>(Sv, Si);
      amax_dpp<DPP_HMIR>(Sv, Si); amax_dpp<DPP_MIR>(Sv, Si);
      amax_xor(Sv, Si, 16);
    }
    const int SiU = __builtin_amdgcn_readfirstlane(Si);
    const unsigned listS = listL[SiU];
    const int Snext = (int)(short)(listS & 0xFFFFu);
    const int Sprev = (int)(short)(listS >> 16);
    const int next2S = next2L[SiU];
    const unsigned listP = listL[p2];
    const int pp = (p >= 0) ? (int)(short)(listP >> 16) : -1;
    const int nj2J = next2L[j2];
    const double rcpP = rcpN[p2];
    const double rcpNN = rcpN[n2];
    const int grp = (w == 0) ? gi_ : (w == 1) ? gp_ : gj_;
    double stv = NEGINF; int sti = 0;
    if (w < 3) {
      const int pos = grp * GS + lane;
      double c = cosL[pos];
      if (pos == i || pos == p || pos == j) c = NEGINF;  // replaced post-B
      int cx = pos;
      amax_dpp<DPP_XOR1>(c, cx); amax_dpp<DPP_XOR2>(c, cx);
      amax_dpp<DPP_HMIR>(c, cx); amax_dpp<DPP_MIR>(c, cx);
      amax_xor(c, cx, 16); amax_xor(c, cx, 32);
      stv = c; sti = cx;
      if (lane == 0) { r4v[w] = c; r4i[w] = cx; }
    }

    // ---- consume loads: tanh, store parent, fused 3-sum, DPP reduce ----
    const double q0 = tanh_fast(fma((double)Lxi0.x, wl0, fma((double)Lxj0.x, wr0, bv0)));
    const double q1 = tanh_fast(fma((double)Lxi0.y, wl1, fma((double)Lxj0.y, wr1, bv1)));
    const double q2 = tanh_fast(fma((double)Lxi1.x, wl2, fma((double)Lxj1.x, wr2, bv2)));
    const double q3 = tanh_fast(fma((double)Lxi1.y, wl3, fma((double)Lxj1.y, wr3, bv3)));
    T2 st0; st0.x = (T)q0; st0.y = (T)q1;
    T2 st1; st1.x = (T)q2; st1.y = (T)q3;
    *(T2*)&x[(size_t)j * EE + e0] = st0;
    *(T2*)&x[(size_t)j * EE + e0 + 512] = st1;
    double s0 = fma(q0, q0, fma(q1, q1, fma(q2, q2, q3 * q3)));
    double s1 = fma((double)Lxp0.x, q0, fma((double)Lxp0.y, q1,
                fma((double)Lxp1.x, q2, (double)Lxp1.y * q3)));
    double s2 = fma(q0, (double)Lxn0.x, fma(q1, (double)Lxn0.y,
                fma(q2, (double)Lxn1.x, q3 * (double)Lxn1.y)));
    s1 = (p >= 0) ? s1 : 0.0;
    s2 = (nj >= 0) ? s2 : 0.0;
    s0 = dpp_add<DPP_XOR1>(s0); s1 = dpp_add<DPP_XOR1>(s1); s2 = dpp_add<DPP_XOR1>(s2);
    s0 = dpp_add<DPP_XOR2>(s0); s1 = dpp_add<DPP_XOR2>(s1); s2 = dpp_add<DPP_XOR2>(s2);
    s0 = dpp_add<DPP_HMIR>(s0); s1 = dpp_add<DPP_HMIR>(s1); s2 = dpp_add<DPP_HMIR>(s2);
    s0 = dpp_add<DPP_MIR>(s0);  s1 = dpp_add<DPP_MIR>(s1);  s2 = dpp_add<DPP_MIR>(s2);
    s0 += __shfl_xor(s0, 16, 64);
    s1 += __shfl_xor(s1, 16, 64);
    s2 += __shfl_xor(s2, 16, 64);
    if ((lane & 31) == 0) {
      const int slot = w * 2 + (lane >> 5);
      r3v[slot * 3 + 0] = s0; r3v[slot * 3 + 1] = s1; r3v[slot * 3 + 2] = s2;
    }
    __syncthreads();  // B

    // ---- post-B: finish sums, cosines, 6-way argmax, select next quad ----
    const double U0v = r4v[0], U1v = r4v[1], U2v = r4v[2];
    const int U0i = r4i[0], U1i = r4i[1], U2i = r4i[2];
    double t0 = 0.0, t1 = 0.0, t2 = 0.0;
#pragma unroll
    for (int m = 0; m < NW * 2; ++m) {
      t0 += r3v[m * 3 + 0]; t1 += r3v[m * 3 + 1]; t2 += r3v[m * 3 + 2];
    }
    const double invnn = (t0 > EPSD * EPSD) ? rsqrt2(t0) : (1.0 / EPSD);
    const double cosP = (p >= 0) ? (t1 * rcpP) * invnn : NEGINF;
    const double cosJ = (nj >= 0) ? (t2 * rcpNN) * invnn : NEGINF;
    double bvv = Sv; int bii = Si;
    foldmax(bvv, bii, U0v, U0i);
    foldmax(bvv, bii, U1v, U1i);
    foldmax(bvv, bii, U2v, U2i);
    foldmax(bvv, bii, cosP, p);
    foldmax(bvv, bii, cosJ, j);
    const int iN = __builtin_amdgcn_readfirstlane(bii);
    int jN, pN, njN;
    if (iN == p)        { jN = j;     pN = pp;    njN = nj;    }
    else if (iN == j)   { jN = nj;    pN = p;     njN = nj2J;  }
    else if (iN == SiU) { jN = Snext; pN = Sprev; njN = next2S; }
    else {
      const unsigned pkiU = listL[iN & (SS - 1)];  // iN not in {p,j}: stable words
      jN = (int)(short)(pkiU & 0xFFFFu);
      pN = (int)(short)(pkiU >> 16);
      njN = next2L[iN & (SS - 1)];
    }
    if (iN != p && iN != j && iN == pp) njN = j;  // next2 staleness fix

    // ---- repairs with OLD (i,j,p): O(1) gVal update + scalar writes ----
    if (w < 3) {
      double nv = stv; int ni = sti;
      if (p >= 0 && (p >> 6) == grp) foldmax(nv, ni, cosP, p);
      if ((j >> 6) == grp) foldmax(nv, ni, cosJ, j);
      if (lane == 0) { gVal[grp] = nv; gIdx[grp] = ni; }
    } else if (lane == 0) {
      cosL[i] = NEGINF;
      cosL[j] = cosJ;           // -inf when nj < 0
      rcpN[j] = invnn;
      listL[j] = ((unsigned)nj & 0xFFFFu) | (((unsigned)p & 0xFFFFu) << 16);
      if (p >= 0) {
        cosL[p] = cosP;
        listL[p] = (listP & 0xFFFF0000u) | ((unsigned)j & 0xFFFFu);
        next2L[p] = nj;
        if (pp >= 0) next2L[pp] = j;
      }
    }
    // commit new quad
    i = iN; j = jN; p = pN; nj = njN;
    p2 = (p >= 0) ? p : i;
    n2 = (nj >= 0) ? nj : i;
    j2 = (j >= 0) ? j : i;
    __syncthreads();  // C
    // ---- issue next step's loads; sched_barrier pins them HERE ----
    ISSUE_LOADS();
  }
#undef ISSUE_LOADS

  {
    const T2 ha = *(const T2*)&x[(size_t)head * EE + e0];
    const T2 hb = *(const T2*)&x[(size_t)head * EE + e0 + 512];
    out[e0] = (float)ha.x;
    out[e0 + 1] = (float)ha.y;
    out[e0 + 512] = (float)hb.x;
    out[e0 + 513] = (float)hb.y;
  }
}

extern "C" void kernel_launch(void* const* d_in, const int* in_sizes, int n_in,
                              void* d_out, int out_size, void* d_ws, size_t ws_size,
                              hipStream_t stream) {
  const int* seqs = (const int*)d_in[0];
  const float* emb = (const float*)d_in[1];
  const float* Wl = (const float*)d_in[2];
  const float* Wr = (const float*)d_in[3];
  const float* Bb = (const float*)d_in[4];
  float* out = (float*)d_out;

  const size_t auxBytes = 2 * (size_t)SS * sizeof(double);
  const size_t xbytesD = (size_t)SS * EE * sizeof(double);

  if (ws_size >= xbytesD + auxBytes) {
    double* x = (double*)d_ws;
    double* norms = (double*)((char*)d_ws + xbytesD);
    double* num = norms + SS;
    hipLaunchKernelGGL((banyan_init<double>), dim3(SS), dim3(256), 0, stream, seqs, emb, x, norms);
    hipLaunchKernelGGL((banyan_dots<double>), dim3(SS - 1), dim3(256), 0, stream, x, num);
    hipLaunchKernelGGL((banyan_main<double>), dim3(1), dim3(NTH), 0, stream,
                       x, norms, num, Wl, Wr, Bb, out);
  } else {
    const size_t xbytesF = (size_t)SS * EE * sizeof(float);
    float* x = (float*)d_ws;
    double* norms = (double*)((char*)d_ws + xbytesF);
    double* num = norms + SS;
    hipLaunchKernelGGL((banyan_init<float>), dim3(SS), dim3(256), 0, stream, seqs, emb, x, norms);
    hipLaunchKernelGGL((banyan_dots<float>), dim3(SS - 1), dim3(256), 0, stream, x, num);
    hipLaunchKernelGGL((banyan_main<float>), dim3(1), dim3(NTH), 0, stream,
                       x, norms, num, Wl, Wr, Bb, out);
  }
}